// Round 1
// baseline (551.266 us; speedup 1.0000x reference)
//
#include <hip/hip_runtime.h>

// ---------------------------------------------------------------------------
// AttentionWithEinops: B=2,S=2048,D=2048,H=16,KVH=4,Dh=128, start_pos input.
// bf16 MFMA everywhere (fp32 accumulate), fp32 outputs.
// d_out = [output 2*2048*2048][k_cache 2*2048*4*128][v_cache 2*2048*4*128]
// ---------------------------------------------------------------------------

typedef __attribute__((ext_vector_type(8))) short frag8;   // 8 x bf16 (4 VGPR)
typedef __attribute__((ext_vector_type(4))) float facc4;   // 4 x f32 acc

#define DEVI __device__ __forceinline__

constexpr int Bc  = 2;
constexpr int Sc  = 2048;
constexpr int Dc  = 2048;
constexpr int Hc  = 16;
constexpr int KVHc = 4;
constexpr int Dhc = 128;
constexpr int Mc  = Bc * Sc;       // 4096
constexpr int NQc = Hc * Dhc;      // 2048
constexpr int NKVc = KVHc * Dhc;   // 512

DEVI unsigned short f2bf(float f) {
  union { float f; unsigned u; } v; v.f = f;
  return (unsigned short)((v.u + 0x7fffu + ((v.u >> 16) & 1u)) >> 16);
}
DEVI float bf2f(unsigned short h) {
  union { unsigned u; float f; } v; v.u = ((unsigned)h) << 16;
  return v.f;
}

DEVI void gload_lds16(const void* g, void* l) {
  __builtin_amdgcn_global_load_lds(
      (const __attribute__((address_space(1))) unsigned int*)g,
      (__attribute__((address_space(3))) unsigned int*)l, 16, 0, 0);
}

// ------------------------------- converters --------------------------------

__global__ void cvt_f32_bf16(const float* __restrict__ in,
                             unsigned short* __restrict__ out, int n) {
  int i = (blockIdx.x * 256 + threadIdx.x) * 4;
  if (i < n) {
    float4 v = *(const float4*)(in + i);
    ushort4 o;
    o.x = f2bf(v.x); o.y = f2bf(v.y); o.z = f2bf(v.z); o.w = f2bf(v.w);
    *(ushort4*)(out + i) = o;
  }
}

// W_O [2048(he)][2048(d)] f32 -> wob [2048(d)][2048(he)] bf16 (transposed)
__global__ void cvt_transpose_wo(const float* __restrict__ in,
                                 unsigned short* __restrict__ out) {
  __shared__ float tile[64][65];
  int r0 = blockIdx.y * 64;   // he base
  int c0 = blockIdx.x * 64;   // d base
  int t = threadIdx.x;
#pragma unroll
  for (int i = 0; i < 16; ++i) {
    int idx = i * 256 + t; int r = idx >> 6, c = idx & 63;
    tile[r][c] = in[(size_t)(r0 + r) * Dc + c0 + c];
  }
  __syncthreads();
#pragma unroll
  for (int i = 0; i < 16; ++i) {
    int idx = i * 256 + t; int r = idx >> 6, c = idx & 63;
    out[(size_t)(c0 + r) * NQc + r0 + c] = f2bf(tile[c][r]);
  }
}

// ------------------------- NT GEMM (m97 structure) -------------------------
// C[M,N] = A[M,K](bf16) * B[N,K](bf16)^T ; 128x128 tile, BK=32, 256 thr.
// WF32: write f32 C. WBF16: write bf16 C. VTRANS: bf16 C written as
// [b][n][s] (n-major transposed per batch, stride S) -- used for V.

template <bool WF32, bool WBF16, bool VTRANS>
__global__ __launch_bounds__(256) void gemm_nt(
    const unsigned short* __restrict__ Amat,
    const unsigned short* __restrict__ Bmat,
    float* __restrict__ Cf, unsigned short* __restrict__ Cb,
    int Nn, int Kk) {
  __shared__ __align__(16) unsigned short As[128 * 32];
  __shared__ __align__(16) unsigned short Bs[128 * 32];
  int t = threadIdx.x;
  int lane = t & 63, w = t >> 6;
  int quad = lane >> 4, l16 = lane & 15;
  int wm = (w >> 1) * 64, wn = (w & 1) * 64;
  int m0 = blockIdx.x * 128, n0 = blockIdx.y * 128;

  facc4 acc[4][4] = {};

  const int nIter = Kk / 32;
  for (int kt = 0; kt < nIter; ++kt) {
    __syncthreads();
#pragma unroll
    for (int i = 0; i < 2; ++i) {
      int c = i * 256 + t;          // 512 chunks of 16B per matrix
      int row = c >> 2, ch = c & 3;
      gload_lds16(Amat + (size_t)(m0 + row) * Kk + kt * 32 + ch * 8, &As[c * 8]);
      gload_lds16(Bmat + (size_t)(n0 + row) * Kk + kt * 32 + ch * 8, &Bs[c * 8]);
    }
    asm volatile("s_waitcnt vmcnt(0)" ::: "memory");
    __syncthreads();

    frag8 aF[4], bF[4];
#pragma unroll
    for (int mi = 0; mi < 4; ++mi)
      aF[mi] = *(const frag8*)&As[(wm + mi * 16 + l16) * 32 + quad * 8];
#pragma unroll
    for (int ni = 0; ni < 4; ++ni)
      bF[ni] = *(const frag8*)&Bs[(wn + ni * 16 + l16) * 32 + quad * 8];
#pragma unroll
    for (int mi = 0; mi < 4; ++mi)
#pragma unroll
      for (int ni = 0; ni < 4; ++ni)
        acc[mi][ni] = __builtin_amdgcn_mfma_f32_16x16x32_bf16(
            aF[mi], bF[ni], acc[mi][ni], 0, 0, 0);
  }

#pragma unroll
  for (int mi = 0; mi < 4; ++mi)
#pragma unroll
    for (int ni = 0; ni < 4; ++ni)
#pragma unroll
      for (int i = 0; i < 4; ++i) {
        int mrow = m0 + wm + mi * 16 + quad * 4 + i;
        int ncol = n0 + wn + ni * 16 + l16;
        float v = acc[mi][ni][i];
        if (WF32) Cf[(size_t)mrow * Nn + ncol] = v;
        if (WBF16) {
          if (VTRANS) {
            int b = mrow >> 11, s = mrow & 2047;
            Cb[((size_t)(b * NKVc + ncol)) * Sc + s] = f2bf(v);
          } else {
            Cb[(size_t)mrow * Nn + ncol] = f2bf(v);
          }
        }
      }
}

// --------------------------------- RoPE ------------------------------------

__global__ void rope_q(unsigned short* qb, const int* __restrict__ sp) {
  int idx = blockIdx.x * 256 + threadIdx.x;  // (m,h,e) e<64 : 4096*16*64
  int e = idx & 63, h = (idx >> 6) & 15, m = idx >> 10;
  int s = m & (Sc - 1);
  float pos = (float)(sp[0] + s);
  float invf = powf(10000.0f, -(float)e / 64.0f);
  float ang = pos * invf;
  float sn, cs; sincosf(ang, &sn, &cs);
  size_t base = (size_t)m * NQc + h * Dhc + e;
  float x1 = bf2f(qb[base]), x2 = bf2f(qb[base + 64]);
  qb[base]      = f2bf(x1 * cs - x2 * sn);
  qb[base + 64] = f2bf(x1 * sn + x2 * cs);
}

// k fp32 (in d_out) roped in place + bf16 copy for attention
__global__ void rope_k(float* kf, unsigned short* kb, const int* __restrict__ sp) {
  int idx = blockIdx.x * 256 + threadIdx.x;  // (m,kvh,e) e<64 : 4096*4*64
  int e = idx & 63, kvh = (idx >> 6) & 3, m = idx >> 8;
  int s = m & (Sc - 1);
  float pos = (float)(sp[0] + s);
  float invf = powf(10000.0f, -(float)e / 64.0f);
  float ang = pos * invf;
  float sn, cs; sincosf(ang, &sn, &cs);
  size_t base = (size_t)m * NKVc + kvh * Dhc + e;
  float x1 = kf[base], x2 = kf[base + 64];
  float o1 = x1 * cs - x2 * sn;
  float o2 = x1 * sn + x2 * cs;
  kf[base] = o1; kf[base + 64] = o2;
  kb[base] = f2bf(o1); kb[base + 64] = f2bf(o2);
}

// ---------------------- flash attention (bf16 MFMA) ------------------------
// WG = (qt, h, b): 64 q-rows, 4 waves x 16 rows. k/v tiles of 64.
// qb doubles as attn output (row-exclusive per WG).

__global__ __launch_bounds__(256) void flash_attn(
    unsigned short* qb,                      // [M][H][Dh] bf16, in+out
    const unsigned short* __restrict__ kb,   // [M][KVH][Dh] bf16 (roped)
    const unsigned short* __restrict__ vbT,  // [B][KVH][Dh][S] bf16
    const int* __restrict__ spp) {
  __shared__ __align__(16) unsigned short Qs[64 * 128];
  __shared__ __align__(16) unsigned short Ks[64 * 128];
  __shared__ __align__(16) unsigned short Vt[128 * 64];
  __shared__ __align__(16) unsigned short Ps[4][16 * 64];

  int qt = blockIdx.x, h = blockIdx.y, b = blockIdx.z;
  int t = threadIdx.x, lane = t & 63, w = t >> 6;
  int quad = lane >> 4, l16 = lane & 15;
  int kvh = h >> 2;
  int sp = spp[0];
  float slope = exp2f(-0.5f * (float)(h + 1));

  // stage Q tile (XOR-swizzled chunks within each 16-chunk row)
#pragma unroll
  for (int i = 0; i < 4; ++i) {
    int c = i * 256 + t;
    int row = c >> 4, chp = c & 15;
    int ch = chp ^ (row & 15);
    gload_lds16(qb + ((size_t)(b * Sc + qt * 64 + row) * NQc) + h * Dhc + ch * 8,
                &Qs[c * 8]);
  }

  facc4 oacc[8] = {};
  float mrow[4], lrow[4];
#pragma unroll
  for (int i = 0; i < 4; ++i) { mrow[i] = -1e30f; lrow[i] = 0.f; }

  int ktlim = (sp + qt * 64 + 63) >> 6;
  int ktmax = ktlim < 31 ? ktlim : 31;

  for (int kt = 0; kt <= ktmax; ++kt) {
    __syncthreads();
#pragma unroll
    for (int i = 0; i < 4; ++i) {
      int c = i * 256 + t;
      int row = c >> 4, chp = c & 15;
      int ch = chp ^ (row & 15);
      gload_lds16(kb + (size_t)(b * Sc + kt * 64 + row) * NKVc + kvh * Dhc + ch * 8,
                  &Ks[c * 8]);
    }
#pragma unroll
    for (int i = 0; i < 4; ++i) {
      int c = i * 256 + t;
      int row = c >> 3, chp = c & 7;       // Vt: 128 rows x 8 chunks
      int ch = chp ^ (row & 7);
      gload_lds16(vbT + ((size_t)(b * KVHc + kvh) * Dhc + row) * Sc + kt * 64 + ch * 8,
                  &Vt[c * 8]);
    }
    asm volatile("s_waitcnt vmcnt(0)" ::: "memory");
    __syncthreads();

    // ---- S = Q K^T (wave rows w*16.., cols 64) ----
    facc4 sacc[4] = {};
#pragma unroll
    for (int kd = 0; kd < 4; ++kd) {
      int ch = kd * 4 + quad;
      frag8 aQ = *(const frag8*)&Qs[(w * 16 + l16) * 128 + (ch ^ l16) * 8];
#pragma unroll
      for (int c4 = 0; c4 < 4; ++c4) {
        frag8 bK = *(const frag8*)&Ks[(c4 * 16 + l16) * 128 + (ch ^ l16) * 8];
        sacc[c4] = __builtin_amdgcn_mfma_f32_16x16x32_bf16(aQ, bK, sacc[c4], 0, 0, 0);
      }
    }

    // ---- scale + alibi + causal mask; row max ----
    float sv[4][4];
    float mt[4] = {-1e30f, -1e30f, -1e30f, -1e30f};
#pragma unroll
    for (int c4 = 0; c4 < 4; ++c4) {
      int kpos = kt * 64 + c4 * 16 + l16;
#pragma unroll
      for (int i = 0; i < 4; ++i) {
        int qrow = qt * 64 + w * 16 + quad * 4 + i;
        int qpos = sp + qrow;
        float v = sacc[c4][i] * 0.08838834764831845f
                  - slope * (float)(qpos - kpos);
        v = (kpos <= qpos) ? v : -1e30f;
        sv[c4][i] = v;
        mt[i] = fmaxf(mt[i], v);
      }
    }
#pragma unroll
    for (int xm = 1; xm < 16; xm <<= 1)
#pragma unroll
      for (int i = 0; i < 4; ++i)
        mt[i] = fmaxf(mt[i], __shfl_xor(mt[i], xm));

    float alpha[4], psum[4];
#pragma unroll
    for (int i = 0; i < 4; ++i) {
      float mn = fmaxf(mrow[i], mt[i]);
      alpha[i] = __expf(mrow[i] - mn);
      mrow[i] = mn;
      psum[i] = 0.f;
    }

    // ---- P = exp(S-m) -> LDS (A-operand layout, swizzled) ----
#pragma unroll
    for (int c4 = 0; c4 < 4; ++c4)
#pragma unroll
      for (int i = 0; i < 4; ++i) {
        float p = __expf(sv[c4][i] - mrow[i]);
        psum[i] += p;
        int r = quad * 4 + i;
        int kk = c4 * 16 + l16;
        Ps[w][r * 64 + ((kk >> 3) ^ (r & 7)) * 8 + (kk & 7)] = f2bf(p);
      }
#pragma unroll
    for (int xm = 1; xm < 16; xm <<= 1)
#pragma unroll
      for (int i = 0; i < 4; ++i)
        psum[i] += __shfl_xor(psum[i], xm);
#pragma unroll
    for (int i = 0; i < 4; ++i)
      lrow[i] = lrow[i] * alpha[i] + psum[i];

    // ---- rescale O, then O += P V ----
#pragma unroll
    for (int c8 = 0; c8 < 8; ++c8)
#pragma unroll
      for (int i = 0; i < 4; ++i)
        oacc[c8][i] *= alpha[i];

#pragma unroll
    for (int k2 = 0; k2 < 2; ++k2) {
      int ch = k2 * 4 + quad;
      frag8 aP = *(const frag8*)&Ps[w][l16 * 64 + (ch ^ (l16 & 7)) * 8];
#pragma unroll
      for (int c8 = 0; c8 < 8; ++c8) {
        frag8 bV = *(const frag8*)&Vt[(c8 * 16 + l16) * 64 + (ch ^ (l16 & 7)) * 8];
        oacc[c8] = __builtin_amdgcn_mfma_f32_16x16x32_bf16(aP, bV, oacc[c8], 0, 0, 0);
      }
    }
  }

  // ---- epilogue: O/l -> attn (in place over qb) ----
  float rinv[4];
#pragma unroll
  for (int i = 0; i < 4; ++i) rinv[i] = 1.0f / lrow[i];
#pragma unroll
  for (int c8 = 0; c8 < 8; ++c8)
#pragma unroll
    for (int i = 0; i < 4; ++i) {
      int row = qt * 64 + w * 16 + quad * 4 + i;
      size_t o = ((size_t)(b * Sc + row) * Hc + h) * Dhc + c8 * 16 + l16;
      qb[o] = f2bf(oacc[c8][i] * rinv[i]);
    }
}

// ------------------------------- launcher ----------------------------------

extern "C" void kernel_launch(void* const* d_in, const int* in_sizes, int n_in,
                              void* d_out, int out_size, void* d_ws, size_t ws_size,
                              hipStream_t stream) {
  const float* residual = (const float*)d_in[0];
  const float* W_Q = (const float*)d_in[1];
  const float* W_K = (const float*)d_in[2];
  const float* W_V = (const float*)d_in[3];
  const float* W_O = (const float*)d_in[4];
  const int* start_pos = (const int*)d_in[5];

  float* out = (float*)d_out;                        // [2][2048][2048]
  float* kf = out + (size_t)Bc * Sc * Dc;            // [4096][512] fp32 k cache
  float* vf = kf + (size_t)Mc * NKVc;                // [4096][512] fp32 v cache

  char* w = (char*)d_ws;
  auto alloc = [&](size_t bytes) {
    char* p = w; w += (bytes + 255) & ~(size_t)255; return p;
  };
  unsigned short* rb  = (unsigned short*)alloc((size_t)Mc * Dc * 2);
  unsigned short* wqb = (unsigned short*)alloc((size_t)NQc * Dc * 2);
  unsigned short* wkb = (unsigned short*)alloc((size_t)NKVc * Dc * 2);
  unsigned short* wvb = (unsigned short*)alloc((size_t)NKVc * Dc * 2);
  unsigned short* wob = (unsigned short*)alloc((size_t)Dc * NQc * 2);
  unsigned short* qb  = (unsigned short*)alloc((size_t)Mc * NQc * 2);
  unsigned short* kb  = (unsigned short*)alloc((size_t)Mc * NKVc * 2);
  unsigned short* vbT = (unsigned short*)alloc((size_t)Mc * NKVc * 2);
  (void)ws_size; (void)in_sizes; (void)n_in; (void)out_size;  // ~63.5 MB used

  cvt_f32_bf16<<<(Mc * Dc) / 1024, 256, 0, stream>>>(residual, rb, Mc * Dc);
  cvt_f32_bf16<<<(NQc * Dc) / 1024, 256, 0, stream>>>(W_Q, wqb, NQc * Dc);
  cvt_f32_bf16<<<(NKVc * Dc) / 1024, 256, 0, stream>>>(W_K, wkb, NKVc * Dc);
  cvt_f32_bf16<<<(NKVc * Dc) / 1024, 256, 0, stream>>>(W_V, wvb, NKVc * Dc);
  cvt_transpose_wo<<<dim3(32, 32), 256, 0, stream>>>(W_O, wob);

  // q (bf16), k (fp32 -> d_out), v (fp32 -> d_out + bf16 transposed)
  gemm_nt<false, true, false><<<dim3(32, 16), 256, 0, stream>>>(rb, wqb, nullptr, qb, NQc, Dc);
  gemm_nt<true, false, false><<<dim3(32, 4), 256, 0, stream>>>(rb, wkb, kf, nullptr, NKVc, Dc);
  gemm_nt<true, true, true><<<dim3(32, 4), 256, 0, stream>>>(rb, wvb, vf, vbT, NKVc, Dc);

  rope_q<<<(Mc * Hc * 64) / 256, 256, 0, stream>>>(qb, start_pos);
  rope_k<<<(Mc * KVHc * 64) / 256, 256, 0, stream>>>(kf, kb, start_pos);

  flash_attn<<<dim3(32, 16, 2), 256, 0, stream>>>(qb, kb, vbT, start_pos);

  // output projection: attn (in qb) x W_O^T -> d_out
  gemm_nt<true, false, false><<<dim3(32, 16), 256, 0, stream>>>(qb, wob, out, nullptr, Dc, Dc);
}

// Round 2
// 452.815 us; speedup vs baseline: 1.2174x; 1.2174x over previous
//
#include <hip/hip_runtime.h>

// ---------------------------------------------------------------------------
// AttentionWithEinops: B=2,S=2048,D=2048,H=16,KVH=4,Dh=128, start_pos input.
// bf16 MFMA everywhere (fp32 accumulate), fp32 outputs.
// d_out = [output 2*2048*2048][k_cache 2*2048*4*128][v_cache 2*2048*4*128]
// ---------------------------------------------------------------------------

typedef __attribute__((ext_vector_type(8))) short frag8;   // 8 x bf16 (4 VGPR)
typedef __attribute__((ext_vector_type(4))) float facc4;   // 4 x f32 acc

#define DEVI __device__ __forceinline__

constexpr int Bc  = 2;
constexpr int Sc  = 2048;
constexpr int Dc  = 2048;
constexpr int Hc  = 16;
constexpr int KVHc = 4;
constexpr int Dhc = 128;
constexpr int Mc  = Bc * Sc;       // 4096
constexpr int NQc = Hc * Dhc;      // 2048
constexpr int NKVc = KVHc * Dhc;   // 512

DEVI unsigned short f2bf(float f) {
  union { float f; unsigned u; } v; v.f = f;
  return (unsigned short)((v.u + 0x7fffu + ((v.u >> 16) & 1u)) >> 16);
}
DEVI float bf2f(unsigned short h) {
  union { unsigned u; float f; } v; v.u = ((unsigned)h) << 16;
  return v.f;
}

DEVI void gload_lds16(const void* g, void* l) {
  __builtin_amdgcn_global_load_lds(
      (const __attribute__((address_space(1))) unsigned int*)g,
      (__attribute__((address_space(3))) unsigned int*)l, 16, 0, 0);
}

// ------------------------------- converters --------------------------------

__global__ void cvt_f32_bf16(const float* __restrict__ in,
                             unsigned short* __restrict__ out, int n) {
  int i = (blockIdx.x * 256 + threadIdx.x) * 4;
  if (i < n) {
    float4 v = *(const float4*)(in + i);
    ushort4 o;
    o.x = f2bf(v.x); o.y = f2bf(v.y); o.z = f2bf(v.z); o.w = f2bf(v.w);
    *(ushort4*)(out + i) = o;
  }
}

// W_O [2048(he)][2048(d)] f32 -> wob [2048(d)][2048(he)] bf16 (transposed)
__global__ void cvt_transpose_wo(const float* __restrict__ in,
                                 unsigned short* __restrict__ out) {
  __shared__ float tile[64][65];
  int r0 = blockIdx.y * 64;   // he base
  int c0 = blockIdx.x * 64;   // d base
  int t = threadIdx.x;
#pragma unroll
  for (int i = 0; i < 16; ++i) {
    int idx = i * 256 + t; int r = idx >> 6, c = idx & 63;
    tile[r][c] = in[(size_t)(r0 + r) * Dc + c0 + c];
  }
  __syncthreads();
#pragma unroll
  for (int i = 0; i < 16; ++i) {
    int idx = i * 256 + t; int r = idx >> 6, c = idx & 63;
    out[(size_t)(c0 + r) * NQc + r0 + c] = f2bf(tile[c][r]);
  }
}

// ------------------------- NT GEMM (m97 structure) -------------------------
// C[M,N] = A[M,K](bf16) * B[N,K](bf16)^T ; 128x128 tile, BK=32, 256 thr.
// MODE 0: f32 C (output projection)
// MODE 1: bf16 C (q projection)
// MODE 2: fused kv: ncol<512 -> k f32; ncol>=512 -> v f32 + v bf16 [b][n][s]

template <int MODE>
__global__ __launch_bounds__(256) void gemm_nt(
    const unsigned short* __restrict__ Amat,
    const unsigned short* __restrict__ Bmat,
    float* __restrict__ Cf, float* __restrict__ Cf2,
    unsigned short* __restrict__ Cb,
    int Nn, int Kk) {
  __shared__ __align__(16) unsigned short As[128 * 32];
  __shared__ __align__(16) unsigned short Bs[128 * 32];
  int t = threadIdx.x;
  int lane = t & 63, w = t >> 6;
  int quad = lane >> 4, l16 = lane & 15;
  int wm = (w >> 1) * 64, wn = (w & 1) * 64;
  int m0 = blockIdx.x * 128, n0 = blockIdx.y * 128;

  facc4 acc[4][4] = {};

  const int nIter = Kk / 32;
  for (int kt = 0; kt < nIter; ++kt) {
    __syncthreads();
#pragma unroll
    for (int i = 0; i < 2; ++i) {
      int c = i * 256 + t;          // 512 chunks of 16B per matrix
      int row = c >> 2, ch = c & 3;
      gload_lds16(Amat + (size_t)(m0 + row) * Kk + kt * 32 + ch * 8, &As[c * 8]);
      gload_lds16(Bmat + (size_t)(n0 + row) * Kk + kt * 32 + ch * 8, &Bs[c * 8]);
    }
    asm volatile("s_waitcnt vmcnt(0)" ::: "memory");
    __syncthreads();

    frag8 aF[4], bF[4];
#pragma unroll
    for (int mi = 0; mi < 4; ++mi)
      aF[mi] = *(const frag8*)&As[(wm + mi * 16 + l16) * 32 + quad * 8];
#pragma unroll
    for (int ni = 0; ni < 4; ++ni)
      bF[ni] = *(const frag8*)&Bs[(wn + ni * 16 + l16) * 32 + quad * 8];
#pragma unroll
    for (int mi = 0; mi < 4; ++mi)
#pragma unroll
      for (int ni = 0; ni < 4; ++ni)
        acc[mi][ni] = __builtin_amdgcn_mfma_f32_16x16x32_bf16(
            aF[mi], bF[ni], acc[mi][ni], 0, 0, 0);
  }

#pragma unroll
  for (int mi = 0; mi < 4; ++mi)
#pragma unroll
    for (int ni = 0; ni < 4; ++ni)
#pragma unroll
      for (int i = 0; i < 4; ++i) {
        int mrow = m0 + wm + mi * 16 + quad * 4 + i;
        int ncol = n0 + wn + ni * 16 + l16;
        float v = acc[mi][ni][i];
        if (MODE == 0) {
          Cf[(size_t)mrow * Nn + ncol] = v;
        } else if (MODE == 1) {
          Cb[(size_t)mrow * Nn + ncol] = f2bf(v);
        } else {
          if (ncol < NKVc) {
            Cf[(size_t)mrow * NKVc + ncol] = v;          // k fp32
          } else {
            int nc = ncol - NKVc;
            Cf2[(size_t)mrow * NKVc + nc] = v;           // v fp32
            int b = mrow >> 11, s = mrow & (Sc - 1);
            Cb[((size_t)(b * NKVc + nc)) * Sc + s] = f2bf(v);  // v^T bf16
          }
        }
      }
}

// --------------------------------- RoPE ------------------------------------

__global__ void rope_q(unsigned short* qb, const int* __restrict__ sp) {
  int idx = blockIdx.x * 256 + threadIdx.x;  // (m,h,e) e<64 : 4096*16*64
  int e = idx & 63, h = (idx >> 6) & 15, m = idx >> 10;
  int s = m & (Sc - 1);
  float pos = (float)(sp[0] + s);
  // inv_freq = 10000^(-e/64) = exp2(-e * log2(10000)/64)
  float invf = exp2f(-(float)e * 0.20762050593046835f);
  float ang = pos * invf;
  float sn, cs; sincosf(ang, &sn, &cs);
  size_t base = (size_t)m * NQc + h * Dhc + e;
  float x1 = bf2f(qb[base]), x2 = bf2f(qb[base + 64]);
  qb[base]      = f2bf(x1 * cs - x2 * sn);
  qb[base + 64] = f2bf(x1 * sn + x2 * cs);
}

// k fp32 (in d_out) roped in place + bf16 copy for attention
__global__ void rope_k(float* kf, unsigned short* kb, const int* __restrict__ sp) {
  int idx = blockIdx.x * 256 + threadIdx.x;  // (m,kvh,e) e<64 : 4096*4*64
  int e = idx & 63, kvh = (idx >> 6) & 3, m = idx >> 8;
  int s = m & (Sc - 1);
  float pos = (float)(sp[0] + s);
  float invf = exp2f(-(float)e * 0.20762050593046835f);
  float ang = pos * invf;
  float sn, cs; sincosf(ang, &sn, &cs);
  size_t base = (size_t)m * NKVc + kvh * Dhc + e;
  float x1 = kf[base], x2 = kf[base + 64];
  float o1 = x1 * cs - x2 * sn;
  float o2 = x1 * sn + x2 * cs;
  kf[base] = o1; kf[base + 64] = o2;
  kb[base] = f2bf(o1); kb[base + 64] = f2bf(o2);
}

// ---------------------- flash attention (bf16 MFMA) ------------------------
// WG = (hb, yq): 64 q-rows, 4 waves x 16 rows. k/v tiles of 64.
// Q fragments live in registers (no Q LDS). LDS = 40 KB -> 4 blocks/CU.
// qb doubles as attn output (row-exclusive per wave).

__global__ __launch_bounds__(256, 4) void flash_attn(
    unsigned short* qb,                      // [M][H][Dh] bf16, in+out
    const unsigned short* __restrict__ kb,   // [M][KVH][Dh] bf16 (roped)
    const unsigned short* __restrict__ vbT,  // [B][KVH][Dh][S] bf16
    const int* __restrict__ spp) {
  __shared__ __align__(16) unsigned short Ks[64 * 128];
  __shared__ __align__(16) unsigned short Vt[128 * 64];
  __shared__ __align__(16) unsigned short Ps[4][16 * 64];

  int hb = blockIdx.x;                // h + 16*b
  int h = hb & 15, b = hb >> 4;
  int yq = blockIdx.y;
  int qt = (yq < 16) ? yq : 47 - yq;  // CU-class load balancing (sum const)
  int t = threadIdx.x, lane = t & 63, w = t >> 6;
  int quad = lane >> 4, l16 = lane & 15;
  int kvh = h >> 2;
  int sp = spp[0];
  constexpr float LOG2E = 1.4426950408889634f;
  const float SC = 0.08838834764831845f * LOG2E;       // 1/sqrt(128)*log2e
  float slope2 = exp2f(-0.5f * (float)(h + 1)) * LOG2E;

  // ---- Q fragments direct from global (A-operand layout) ----
  frag8 aQ[4];
  {
    const unsigned short* qrow =
        qb + (size_t)(b * Sc + qt * 64 + w * 16 + l16) * NQc + h * Dhc;
#pragma unroll
    for (int kd = 0; kd < 4; ++kd)
      aQ[kd] = *(const frag8*)(qrow + (kd * 4 + quad) * 8);
  }

  facc4 oacc[8] = {};
  float mrow[4], lrow[4];
#pragma unroll
  for (int i = 0; i < 4; ++i) { mrow[i] = -1e30f; lrow[i] = 0.f; }

  int ktlim = (sp + qt * 64 + 63) >> 6;
  int ktmax = ktlim < 31 ? ktlim : 31;

  for (int kt = 0; kt <= ktmax; ++kt) {
    __syncthreads();
#pragma unroll
    for (int i = 0; i < 4; ++i) {
      int c = i * 256 + t;
      int row = c >> 4, chp = c & 15;
      int ch = chp ^ (row & 15);
      gload_lds16(kb + (size_t)(b * Sc + kt * 64 + row) * NKVc + kvh * Dhc + ch * 8,
                  &Ks[c * 8]);
    }
#pragma unroll
    for (int i = 0; i < 4; ++i) {
      int c = i * 256 + t;
      int row = c >> 3, chp = c & 7;       // Vt: 128 rows x 8 chunks
      int ch = chp ^ (row & 7);
      gload_lds16(vbT + ((size_t)(b * KVHc + kvh) * Dhc + row) * Sc + kt * 64 + ch * 8,
                  &Vt[c * 8]);
    }
    asm volatile("s_waitcnt vmcnt(0)" ::: "memory");
    __syncthreads();

    // ---- S = Q K^T (wave rows w*16.., cols 64) ----
    facc4 sacc[4] = {};
#pragma unroll
    for (int kd = 0; kd < 4; ++kd) {
      int ch = kd * 4 + quad;
#pragma unroll
      for (int c4 = 0; c4 < 4; ++c4) {
        frag8 bK = *(const frag8*)&Ks[(c4 * 16 + l16) * 128 + (ch ^ l16) * 8];
        sacc[c4] = __builtin_amdgcn_mfma_f32_16x16x32_bf16(aQ[kd], bK, sacc[c4], 0, 0, 0);
      }
    }

    // ---- scale + alibi + causal mask (log2 domain); row max ----
    bool needmask = (kt * 64 + 63) > (sp + qt * 64);
    float sv[4][4];
    float mt[4] = {-1e30f, -1e30f, -1e30f, -1e30f};
#pragma unroll
    for (int c4 = 0; c4 < 4; ++c4) {
      int kpos = kt * 64 + c4 * 16 + l16;
#pragma unroll
      for (int i = 0; i < 4; ++i) {
        int qrow = qt * 64 + w * 16 + quad * 4 + i;
        int qpos = sp + qrow;
        float v = sacc[c4][i] * SC - slope2 * (float)(qpos - kpos);
        if (needmask) v = (kpos <= qpos) ? v : -1e30f;
        sv[c4][i] = v;
        mt[i] = fmaxf(mt[i], v);
      }
    }
#pragma unroll
    for (int xm = 1; xm < 16; xm <<= 1)
#pragma unroll
      for (int i = 0; i < 4; ++i)
        mt[i] = fmaxf(mt[i], __shfl_xor(mt[i], xm));

    float alpha[4], psum[4];
#pragma unroll
    for (int i = 0; i < 4; ++i) {
      float mn = fmaxf(mrow[i], mt[i]);
      alpha[i] = exp2f(mrow[i] - mn);
      mrow[i] = mn;
      psum[i] = 0.f;
    }

    // ---- P = exp2(S-m) -> LDS (A-operand layout, swizzled) ----
#pragma unroll
    for (int c4 = 0; c4 < 4; ++c4)
#pragma unroll
      for (int i = 0; i < 4; ++i) {
        float p = exp2f(sv[c4][i] - mrow[i]);
        psum[i] += p;
        int r = quad * 4 + i;
        int kk = c4 * 16 + l16;
        Ps[w][r * 64 + ((kk >> 3) ^ (r & 7)) * 8 + (kk & 7)] = f2bf(p);
      }
#pragma unroll
    for (int xm = 1; xm < 16; xm <<= 1)
#pragma unroll
      for (int i = 0; i < 4; ++i)
        psum[i] += __shfl_xor(psum[i], xm);
#pragma unroll
    for (int i = 0; i < 4; ++i)
      lrow[i] = lrow[i] * alpha[i] + psum[i];

    // ---- rescale O, then O += P V ----
#pragma unroll
    for (int c8 = 0; c8 < 8; ++c8)
#pragma unroll
      for (int i = 0; i < 4; ++i)
        oacc[c8][i] *= alpha[i];

#pragma unroll
    for (int k2 = 0; k2 < 2; ++k2) {
      int ch = k2 * 4 + quad;
      frag8 aP = *(const frag8*)&Ps[w][l16 * 64 + (ch ^ (l16 & 7)) * 8];
#pragma unroll
      for (int c8 = 0; c8 < 8; ++c8) {
        frag8 bV = *(const frag8*)&Vt[(c8 * 16 + l16) * 64 + (ch ^ (l16 & 7)) * 8];
        oacc[c8] = __builtin_amdgcn_mfma_f32_16x16x32_bf16(aP, bV, oacc[c8], 0, 0, 0);
      }
    }
  }

  // ---- epilogue: O/l -> attn (in place over qb) ----
  float rinv[4];
#pragma unroll
  for (int i = 0; i < 4; ++i) rinv[i] = 1.0f / lrow[i];
#pragma unroll
  for (int c8 = 0; c8 < 8; ++c8)
#pragma unroll
    for (int i = 0; i < 4; ++i) {
      int row = qt * 64 + w * 16 + quad * 4 + i;
      size_t o = ((size_t)(b * Sc + row) * Hc + h) * Dhc + c8 * 16 + l16;
      qb[o] = f2bf(oacc[c8][i] * rinv[i]);
    }
}

// ------------------------------- launcher ----------------------------------

extern "C" void kernel_launch(void* const* d_in, const int* in_sizes, int n_in,
                              void* d_out, int out_size, void* d_ws, size_t ws_size,
                              hipStream_t stream) {
  const float* residual = (const float*)d_in[0];
  const float* W_Q = (const float*)d_in[1];
  const float* W_K = (const float*)d_in[2];
  const float* W_V = (const float*)d_in[3];
  const float* W_O = (const float*)d_in[4];
  const int* start_pos = (const int*)d_in[5];

  float* out = (float*)d_out;                        // [2][2048][2048]
  float* kf = out + (size_t)Bc * Sc * Dc;            // [4096][512] fp32 k cache
  float* vf = kf + (size_t)Mc * NKVc;                // [4096][512] fp32 v cache

  char* w = (char*)d_ws;
  auto alloc = [&](size_t bytes) {
    char* p = w; w += (bytes + 255) & ~(size_t)255; return p;
  };
  unsigned short* rb   = (unsigned short*)alloc((size_t)Mc * Dc * 2);
  unsigned short* wqb  = (unsigned short*)alloc((size_t)NQc * Dc * 2);
  unsigned short* wkvb = (unsigned short*)alloc((size_t)2 * NKVc * Dc * 2); // [K;V]
  unsigned short* wob  = (unsigned short*)alloc((size_t)Dc * NQc * 2);
  unsigned short* qb   = (unsigned short*)alloc((size_t)Mc * NQc * 2);
  unsigned short* kb   = (unsigned short*)alloc((size_t)Mc * NKVc * 2);
  unsigned short* vbT  = (unsigned short*)alloc((size_t)Mc * NKVc * 2);
  (void)ws_size; (void)in_sizes; (void)n_in; (void)out_size;

  cvt_f32_bf16<<<(Mc * Dc) / 1024, 256, 0, stream>>>(residual, rb, Mc * Dc);
  cvt_f32_bf16<<<(NQc * Dc) / 1024, 256, 0, stream>>>(W_Q, wqb, NQc * Dc);
  cvt_f32_bf16<<<(NKVc * Dc) / 1024, 256, 0, stream>>>(W_K, wkvb, NKVc * Dc);
  cvt_f32_bf16<<<(NKVc * Dc) / 1024, 256, 0, stream>>>(W_V, wkvb + (size_t)NKVc * Dc, NKVc * Dc);
  cvt_transpose_wo<<<dim3(32, 32), 256, 0, stream>>>(W_O, wob);

  // q (bf16); fused k+v (k fp32 -> d_out; v fp32 -> d_out + bf16 transposed)
  gemm_nt<1><<<dim3(32, 16), 256, 0, stream>>>(rb, wqb, nullptr, nullptr, qb, NQc, Dc);
  gemm_nt<2><<<dim3(32, 8), 256, 0, stream>>>(rb, wkvb, kf, vf, vbT, 2 * NKVc, Dc);

  rope_q<<<(Mc * Hc * 64) / 256, 256, 0, stream>>>(qb, start_pos);
  rope_k<<<(Mc * KVHc * 64) / 256, 256, 0, stream>>>(kf, kb, start_pos);

  flash_attn<<<dim3(32, 32), 256, 0, stream>>>(qb, kb, vbT, start_pos);

  // output projection: attn (in qb) x W_O^T -> d_out
  gemm_nt<0><<<dim3(32, 16), 256, 0, stream>>>(qb, wob, out, nullptr, nullptr, Dc, Dc);
}

// Round 3
// 397.646 us; speedup vs baseline: 1.3863x; 1.1387x over previous
//
#include <hip/hip_runtime.h>

// ---------------------------------------------------------------------------
// AttentionWithEinops: B=2,S=2048,D=2048,H=16,KVH=4,Dh=128, start_pos input.
// bf16 MFMA everywhere (fp32 accumulate), fp32 outputs.
// d_out = [output 2*2048*2048][k_cache 2*2048*4*128][v_cache 2*2048*4*128]
// ---------------------------------------------------------------------------

typedef __attribute__((ext_vector_type(8))) short frag8;   // 8 x bf16 (4 VGPR)
typedef __attribute__((ext_vector_type(4))) float facc4;   // 4 x f32 acc

#define DEVI __device__ __forceinline__

constexpr int Bc  = 2;
constexpr int Sc  = 2048;
constexpr int Dc  = 2048;
constexpr int Hc  = 16;
constexpr int KVHc = 4;
constexpr int Dhc = 128;
constexpr int Mc  = Bc * Sc;       // 4096
constexpr int NQc = Hc * Dhc;      // 2048
constexpr int NKVc = KVHc * Dhc;   // 512

DEVI unsigned short f2bf(float f) {
  union { float f; unsigned u; } v; v.f = f;
  return (unsigned short)((v.u + 0x7fffu + ((v.u >> 16) & 1u)) >> 16);
}
DEVI float bf2f(unsigned short h) {
  union { unsigned u; float f; } v; v.u = ((unsigned)h) << 16;
  return v.f;
}

DEVI void gload_lds16(const void* g, void* l) {
  __builtin_amdgcn_global_load_lds(
      (const __attribute__((address_space(1))) unsigned int*)g,
      (__attribute__((address_space(3))) unsigned int*)l, 16, 0, 0);
}

// DPP rotate-combine reduce over the 16-lane row (no LDS traffic).
// Cumulative ror {8,4,2,1} covers each of the 16 lanes exactly once.
DEVI float rowred_max(float x) {
  union { float f; int i; } a, b;
  a.f = x;
  b.i = __builtin_amdgcn_update_dpp(a.i, a.i, 0x128, 0xF, 0xF, false); a.f = fmaxf(a.f, b.f);
  b.i = __builtin_amdgcn_update_dpp(a.i, a.i, 0x124, 0xF, 0xF, false); a.f = fmaxf(a.f, b.f);
  b.i = __builtin_amdgcn_update_dpp(a.i, a.i, 0x122, 0xF, 0xF, false); a.f = fmaxf(a.f, b.f);
  b.i = __builtin_amdgcn_update_dpp(a.i, a.i, 0x121, 0xF, 0xF, false); a.f = fmaxf(a.f, b.f);
  return a.f;
}
DEVI float rowred_sum(float x) {
  union { float f; int i; } a, b;
  a.f = x;
  b.i = __builtin_amdgcn_update_dpp(a.i, a.i, 0x128, 0xF, 0xF, false); a.f += b.f;
  b.i = __builtin_amdgcn_update_dpp(a.i, a.i, 0x124, 0xF, 0xF, false); a.f += b.f;
  b.i = __builtin_amdgcn_update_dpp(a.i, a.i, 0x122, 0xF, 0xF, false); a.f += b.f;
  b.i = __builtin_amdgcn_update_dpp(a.i, a.i, 0x121, 0xF, 0xF, false); a.f += b.f;
  return a.f;
}

// ------------------------------- converters --------------------------------

__global__ void cvt_f32_bf16(const float* __restrict__ in,
                             unsigned short* __restrict__ out, int n) {
  int i = (blockIdx.x * 256 + threadIdx.x) * 4;
  if (i < n) {
    float4 v = *(const float4*)(in + i);
    ushort4 o;
    o.x = f2bf(v.x); o.y = f2bf(v.y); o.z = f2bf(v.z); o.w = f2bf(v.w);
    *(ushort4*)(out + i) = o;
  }
}

// W_O [2048(he)][2048(d)] f32 -> wob [2048(d)][2048(he)] bf16 (transposed)
__global__ void cvt_transpose_wo(const float* __restrict__ in,
                                 unsigned short* __restrict__ out) {
  __shared__ float tile[64][65];
  int r0 = blockIdx.y * 64;   // he base
  int c0 = blockIdx.x * 64;   // d base
  int t = threadIdx.x;
#pragma unroll
  for (int i = 0; i < 16; ++i) {
    int idx = i * 256 + t; int r = idx >> 6, c = idx & 63;
    tile[r][c] = in[(size_t)(r0 + r) * Dc + c0 + c];
  }
  __syncthreads();
#pragma unroll
  for (int i = 0; i < 16; ++i) {
    int idx = i * 256 + t; int r = idx >> 6, c = idx & 63;
    out[(size_t)(c0 + r) * NQc + r0 + c] = f2bf(tile[c][r]);
  }
}

// ------------------------- NT GEMM (m97 structure) -------------------------
// C[M,N] = A[M,K](bf16) * B[N,K](bf16)^T ; 128x128 tile, BK=32, 256 thr.
// MODE 0: f32 C (output projection)
// MODE 1: bf16 C (q projection)
// MODE 2: fused kv: ncol<512 -> k f32; ncol>=512 -> v f32 + v bf16 [b][n][s]

template <int MODE>
__global__ __launch_bounds__(256) void gemm_nt(
    const unsigned short* __restrict__ Amat,
    const unsigned short* __restrict__ Bmat,
    float* __restrict__ Cf, float* __restrict__ Cf2,
    unsigned short* __restrict__ Cb,
    int Nn, int Kk) {
  __shared__ __align__(16) unsigned short As[128 * 32];
  __shared__ __align__(16) unsigned short Bs[128 * 32];
  int t = threadIdx.x;
  int lane = t & 63, w = t >> 6;
  int quad = lane >> 4, l16 = lane & 15;
  int wm = (w >> 1) * 64, wn = (w & 1) * 64;
  int m0 = blockIdx.x * 128, n0 = blockIdx.y * 128;

  facc4 acc[4][4] = {};

  const int nIter = Kk / 32;
  for (int kt = 0; kt < nIter; ++kt) {
    __syncthreads();
#pragma unroll
    for (int i = 0; i < 2; ++i) {
      int c = i * 256 + t;          // 512 chunks of 16B per matrix
      int row = c >> 2, ch = c & 3;
      gload_lds16(Amat + (size_t)(m0 + row) * Kk + kt * 32 + ch * 8, &As[c * 8]);
      gload_lds16(Bmat + (size_t)(n0 + row) * Kk + kt * 32 + ch * 8, &Bs[c * 8]);
    }
    asm volatile("s_waitcnt vmcnt(0)" ::: "memory");
    __syncthreads();

    frag8 aF[4], bF[4];
#pragma unroll
    for (int mi = 0; mi < 4; ++mi)
      aF[mi] = *(const frag8*)&As[(wm + mi * 16 + l16) * 32 + quad * 8];
#pragma unroll
    for (int ni = 0; ni < 4; ++ni)
      bF[ni] = *(const frag8*)&Bs[(wn + ni * 16 + l16) * 32 + quad * 8];
#pragma unroll
    for (int mi = 0; mi < 4; ++mi)
#pragma unroll
      for (int ni = 0; ni < 4; ++ni)
        acc[mi][ni] = __builtin_amdgcn_mfma_f32_16x16x32_bf16(
            aF[mi], bF[ni], acc[mi][ni], 0, 0, 0);
  }

#pragma unroll
  for (int mi = 0; mi < 4; ++mi)
#pragma unroll
    for (int ni = 0; ni < 4; ++ni)
#pragma unroll
      for (int i = 0; i < 4; ++i) {
        int mrow = m0 + wm + mi * 16 + quad * 4 + i;
        int ncol = n0 + wn + ni * 16 + l16;
        float v = acc[mi][ni][i];
        if (MODE == 0) {
          Cf[(size_t)mrow * Nn + ncol] = v;
        } else if (MODE == 1) {
          Cb[(size_t)mrow * Nn + ncol] = f2bf(v);
        } else {
          if (ncol < NKVc) {
            Cf[(size_t)mrow * NKVc + ncol] = v;          // k fp32
          } else {
            int nc = ncol - NKVc;
            Cf2[(size_t)mrow * NKVc + nc] = v;           // v fp32
            int b = mrow >> 11, s = mrow & (Sc - 1);
            Cb[((size_t)(b * NKVc + nc)) * Sc + s] = f2bf(v);  // v^T bf16
          }
        }
      }
}

// --------------------------------- RoPE ------------------------------------

__global__ void rope_q(unsigned short* qb, const int* __restrict__ sp) {
  int idx = blockIdx.x * 256 + threadIdx.x;  // (m,h,e) e<64 : 4096*16*64
  int e = idx & 63, h = (idx >> 6) & 15, m = idx >> 10;
  int s = m & (Sc - 1);
  float pos = (float)(sp[0] + s);
  float invf = exp2f(-(float)e * 0.20762050593046835f);
  float ang = pos * invf;
  float sn, cs; sincosf(ang, &sn, &cs);
  size_t base = (size_t)m * NQc + h * Dhc + e;
  float x1 = bf2f(qb[base]), x2 = bf2f(qb[base + 64]);
  qb[base]      = f2bf(x1 * cs - x2 * sn);
  qb[base + 64] = f2bf(x1 * sn + x2 * cs);
}

__global__ void rope_k(float* kf, unsigned short* kb, const int* __restrict__ sp) {
  int idx = blockIdx.x * 256 + threadIdx.x;  // (m,kvh,e) e<64 : 4096*4*64
  int e = idx & 63, kvh = (idx >> 6) & 3, m = idx >> 8;
  int s = m & (Sc - 1);
  float pos = (float)(sp[0] + s);
  float invf = exp2f(-(float)e * 0.20762050593046835f);
  float ang = pos * invf;
  float sn, cs; sincosf(ang, &sn, &cs);
  size_t base = (size_t)m * NKVc + kvh * Dhc + e;
  float x1 = kf[base], x2 = kf[base + 64];
  float o1 = x1 * cs - x2 * sn;
  float o2 = x1 * sn + x2 * cs;
  kf[base] = o1; kf[base + 64] = o2;
  kb[base] = f2bf(o1); kb[base + 64] = f2bf(o2);
}

// ---------------------- flash attention (bf16 MFMA) ------------------------
// Block = 256 thr (4 waves x 16 q-rows), q-tile pair (qt, 31-qt) -> uniform
// 33 k-tiles/block. K/V double-buffered in LDS (72 KB, 2 blocks/CU), raw
// s_barrier + s_waitcnt vmcnt(8) pipeline (prefetch next tile overlaps
// compute). XCD-swizzled block id: one (b,kvh) group per XCD (K/V L2-resident).

DEVI void issue_tile(const unsigned short* kb, const unsigned short* vbT,
                     int bb, int kvh, int kt, int t,
                     unsigned short* KsB, unsigned short* VtB) {
#pragma unroll
  for (int i = 0; i < 4; ++i) {
    int c = i * 256 + t;
    int row = c >> 4, chp = c & 15;
    int ch = chp ^ (row & 15);
    gload_lds16(kb + (size_t)(bb * Sc + kt * 64 + row) * NKVc + kvh * Dhc + ch * 8,
                KsB + c * 8);
  }
#pragma unroll
  for (int i = 0; i < 4; ++i) {
    int c = i * 256 + t;
    int row = c >> 3, chp = c & 7;       // Vt: 128 rows x 8 chunks
    int ch = chp ^ (row & 7);
    gload_lds16(vbT + ((size_t)(bb * KVHc + kvh) * Dhc + row) * Sc + kt * 64 + ch * 8,
                VtB + c * 8);
  }
}

DEVI void load_q(frag8 (&aQc)[4], const unsigned short* qb, int bb, int qt,
                 int h, int w, int quad, int l16) {
  const unsigned short* qrow =
      qb + (size_t)(bb * Sc + qt * 64 + w * 16 + l16) * NQc + h * Dhc;
#pragma unroll
  for (int kd = 0; kd < 4; ++kd)
    aQc[kd] = *(const frag8*)(qrow + (kd * 4 + quad) * 8);
}

DEVI void write_o(unsigned short* qb, facc4 (&oacc)[8], float (&lrow)[4],
                  int bb, int qt, int h, int w, int quad, int l16) {
  float rinv[4];
#pragma unroll
  for (int i = 0; i < 4; ++i) rinv[i] = 1.0f / lrow[i];
#pragma unroll
  for (int c8 = 0; c8 < 8; ++c8)
#pragma unroll
    for (int i = 0; i < 4; ++i) {
      int row = qt * 64 + w * 16 + quad * 4 + i;
      size_t o = ((size_t)(bb * Sc + row) * Hc + h) * Dhc + c8 * 16 + l16;
      qb[o] = f2bf(oacc[c8][i] * rinv[i]);
    }
}

__global__ __launch_bounds__(256, 2) void flash_attn(
    unsigned short* qb,                      // [M][H][Dh] bf16, in+out
    const unsigned short* __restrict__ kb,   // [M][KVH][Dh] bf16 (roped)
    const unsigned short* __restrict__ vbT,  // [B][KVH][Dh][S] bf16
    const int* __restrict__ spp) {
  __shared__ __align__(16) unsigned short Ks[2][64 * 128];
  __shared__ __align__(16) unsigned short Vt[2][128 * 64];
  __shared__ __align__(16) unsigned short Ps[4][16 * 64];

  // XCD swizzle: group g = (b,kvh) pinned to XCD g (blockId % 8 = XCD).
  int g = blockIdx.x & 7;
  int bb = g >> 2, kvh = g & 3;
  int inner = blockIdx.x >> 3;          // 0..63: 16 pairs x 4 heads-in-group
  int pair = inner & 15, hh = inner >> 4;
  int h = kvh * 4 + hh;
  int qtA = pair, qtB = 31 - pair;

  int t = threadIdx.x, lane = t & 63, w = t >> 6;
  int quad = lane >> 4, l16 = lane & 15;
  int sp = spp[0];
  constexpr float LOG2E = 1.4426950408889634f;
  const float SC = 0.08838834764831845f * LOG2E;       // 1/sqrt(128)*log2e
  float slope2 = exp2f(-0.5f * (float)(h + 1)) * LOG2E;

  int tA = min((sp + qtA * 64 + 63) >> 6, 31) + 1;
  int tB = min((sp + qtB * 64 + 63) >> 6, 31) + 1;
  int total = tA + tB;

  frag8 aQc[4];
  load_q(aQc, qb, bb, qtA, h, w, quad, l16);

  facc4 oacc[8] = {};
  float mrow[4], lrow[4];
#pragma unroll
  for (int i = 0; i < 4; ++i) { mrow[i] = -1e30f; lrow[i] = 0.f; }

  issue_tile(kb, vbT, bb, kvh, 0, t, Ks[0], Vt[0]);

  int qt = qtA;
  for (int it = 0; it < total; ++it) {
    if (it == tA) {
      // finalize part A, switch to part B (stores drain before vmcnt(8) wait)
      write_o(qb, oacc, lrow, bb, qtA, h, w, quad, l16);
      load_q(aQc, qb, bb, qtB, h, w, quad, l16);
#pragma unroll
      for (int c8 = 0; c8 < 8; ++c8)
#pragma unroll
        for (int i = 0; i < 4; ++i) oacc[c8][i] = 0.f;
#pragma unroll
      for (int i = 0; i < 4; ++i) { mrow[i] = -1e30f; lrow[i] = 0.f; }
      qt = qtB;
    }
    int kt = (it < tA) ? it : it - tA;

    if (it + 1 < total) {
      int nk = (it + 1 < tA) ? it + 1 : it + 1 - tA;
      issue_tile(kb, vbT, bb, kvh, nk, t, Ks[(it + 1) & 1], Vt[(it + 1) & 1]);
      asm volatile("s_waitcnt vmcnt(8)" ::: "memory");  // tile it done; it+1 in flight
    } else {
      asm volatile("s_waitcnt vmcnt(0)" ::: "memory");
    }
    __builtin_amdgcn_s_barrier();
    asm volatile("" ::: "memory");

    const unsigned short* KsB = Ks[it & 1];
    const unsigned short* VtB = Vt[it & 1];

    // ---- S = Q K^T (wave rows w*16.., cols 64) ----
    facc4 sacc[4] = {};
#pragma unroll
    for (int kd = 0; kd < 4; ++kd) {
      int ch = kd * 4 + quad;
#pragma unroll
      for (int c4 = 0; c4 < 4; ++c4) {
        frag8 bK = *(const frag8*)&KsB[(c4 * 16 + l16) * 128 + (ch ^ l16) * 8];
        sacc[c4] = __builtin_amdgcn_mfma_f32_16x16x32_bf16(aQc[kd], bK, sacc[c4], 0, 0, 0);
      }
    }

    // ---- scale + alibi + causal mask (log2 domain); row max (DPP) ----
    bool needmask = (kt * 64 + 63) > (sp + qt * 64);
    float sv[4][4];
    float mt[4] = {-1e30f, -1e30f, -1e30f, -1e30f};
#pragma unroll
    for (int c4 = 0; c4 < 4; ++c4) {
      int kpos = kt * 64 + c4 * 16 + l16;
#pragma unroll
      for (int i = 0; i < 4; ++i) {
        int qrow = qt * 64 + w * 16 + quad * 4 + i;
        int qpos = sp + qrow;
        float v = sacc[c4][i] * SC - slope2 * (float)(qpos - kpos);
        if (needmask) v = (kpos <= qpos) ? v : -1e30f;
        sv[c4][i] = v;
        mt[i] = fmaxf(mt[i], v);
      }
    }
#pragma unroll
    for (int i = 0; i < 4; ++i) mt[i] = rowred_max(mt[i]);

    float alpha[4], psum[4];
#pragma unroll
    for (int i = 0; i < 4; ++i) {
      float mn = fmaxf(mrow[i], mt[i]);
      alpha[i] = exp2f(mrow[i] - mn);
      mrow[i] = mn;
      psum[i] = 0.f;
    }

    // ---- P = exp2(S-m) -> LDS (A-operand layout, swizzled) ----
#pragma unroll
    for (int c4 = 0; c4 < 4; ++c4)
#pragma unroll
      for (int i = 0; i < 4; ++i) {
        float p = exp2f(sv[c4][i] - mrow[i]);
        psum[i] += p;
        int r = quad * 4 + i;
        int kk = c4 * 16 + l16;
        Ps[w][r * 64 + ((kk >> 3) ^ (r & 7)) * 8 + (kk & 7)] = f2bf(p);
      }
#pragma unroll
    for (int i = 0; i < 4; ++i) {
      psum[i] = rowred_sum(psum[i]);
      lrow[i] = lrow[i] * alpha[i] + psum[i];
    }

    // ---- rescale O, then O += P V ----
#pragma unroll
    for (int c8 = 0; c8 < 8; ++c8)
#pragma unroll
      for (int i = 0; i < 4; ++i)
        oacc[c8][i] *= alpha[i];

#pragma unroll
    for (int k2 = 0; k2 < 2; ++k2) {
      int ch = k2 * 4 + quad;
      frag8 aP = *(const frag8*)&Ps[w][l16 * 64 + (ch ^ (l16 & 7)) * 8];
#pragma unroll
      for (int c8 = 0; c8 < 8; ++c8) {
        frag8 bV = *(const frag8*)&VtB[(c8 * 16 + l16) * 64 + (ch ^ (l16 & 7)) * 8];
        oacc[c8] = __builtin_amdgcn_mfma_f32_16x16x32_bf16(aP, bV, oacc[c8], 0, 0, 0);
      }
    }

    asm volatile("" ::: "memory");
    __builtin_amdgcn_s_barrier();
  }

  write_o(qb, oacc, lrow, bb, qtB, h, w, quad, l16);
}

// ------------------------------- launcher ----------------------------------

extern "C" void kernel_launch(void* const* d_in, const int* in_sizes, int n_in,
                              void* d_out, int out_size, void* d_ws, size_t ws_size,
                              hipStream_t stream) {
  const float* residual = (const float*)d_in[0];
  const float* W_Q = (const float*)d_in[1];
  const float* W_K = (const float*)d_in[2];
  const float* W_V = (const float*)d_in[3];
  const float* W_O = (const float*)d_in[4];
  const int* start_pos = (const int*)d_in[5];

  float* out = (float*)d_out;                        // [2][2048][2048]
  float* kf = out + (size_t)Bc * Sc * Dc;            // [4096][512] fp32 k cache
  float* vf = kf + (size_t)Mc * NKVc;                // [4096][512] fp32 v cache

  char* w = (char*)d_ws;
  auto alloc = [&](size_t bytes) {
    char* p = w; w += (bytes + 255) & ~(size_t)255; return p;
  };
  unsigned short* rb   = (unsigned short*)alloc((size_t)Mc * Dc * 2);
  unsigned short* wqb  = (unsigned short*)alloc((size_t)NQc * Dc * 2);
  unsigned short* wkvb = (unsigned short*)alloc((size_t)2 * NKVc * Dc * 2); // [K;V]
  unsigned short* wob  = (unsigned short*)alloc((size_t)Dc * NQc * 2);
  unsigned short* qb   = (unsigned short*)alloc((size_t)Mc * NQc * 2);
  unsigned short* kb   = (unsigned short*)alloc((size_t)Mc * NKVc * 2);
  unsigned short* vbT  = (unsigned short*)alloc((size_t)Mc * NKVc * 2);
  (void)ws_size; (void)in_sizes; (void)n_in; (void)out_size;

  cvt_f32_bf16<<<(Mc * Dc) / 1024, 256, 0, stream>>>(residual, rb, Mc * Dc);
  cvt_f32_bf16<<<(NQc * Dc) / 1024, 256, 0, stream>>>(W_Q, wqb, NQc * Dc);
  cvt_f32_bf16<<<(NKVc * Dc) / 1024, 256, 0, stream>>>(W_K, wkvb, NKVc * Dc);
  cvt_f32_bf16<<<(NKVc * Dc) / 1024, 256, 0, stream>>>(W_V, wkvb + (size_t)NKVc * Dc, NKVc * Dc);
  cvt_transpose_wo<<<dim3(32, 32), 256, 0, stream>>>(W_O, wob);

  // q (bf16); fused k+v (k fp32 -> d_out; v fp32 -> d_out + bf16 transposed)
  gemm_nt<1><<<dim3(32, 16), 256, 0, stream>>>(rb, wqb, nullptr, nullptr, qb, NQc, Dc);
  gemm_nt<2><<<dim3(32, 8), 256, 0, stream>>>(rb, wkvb, kf, vf, vbT, 2 * NKVc, Dc);

  rope_q<<<(Mc * Hc * 64) / 256, 256, 0, stream>>>(qb, start_pos);
  rope_k<<<(Mc * KVHc * 64) / 256, 256, 0, stream>>>(kf, kb, start_pos);

  flash_attn<<<512, 256, 0, stream>>>(qb, kb, vbT, start_pos);

  // output projection: attn (in qb) x W_O^T -> d_out
  gemm_nt<0><<<dim3(32, 16), 256, 0, stream>>>(qb, wob, out, nullptr, nullptr, Dc, Dc);
}